// Round 15
// baseline (255.087 us; speedup 1.0000x reference)
//
#include <hip/hip_runtime.h>
#include <hip/hip_bf16.h>

// ---------------- common ----------------
typedef __attribute__((ext_vector_type(4))) int i32x4;

#define M_DIM 8192
#define N_DIM 4096
#define K_DIM 4096
#define BM 256
#define BN 256
#define BK 128
#define NT2 (K_DIM / BK)  // 32

static __device__ inline void gload_lds16(const void* g, void* l) {
  __builtin_amdgcn_global_load_lds(
      (const __attribute__((address_space(1))) unsigned int*)g,
      (__attribute__((address_space(3))) unsigned int*)l,
      16, 0, 0);
}

// ---------------- prep: x fp32 -> i8 (per-row symmetric), row scale + int row-sum ----------------
__global__ __launch_bounds__(256) void prep_x_i8(
    const float* __restrict__ x, char* __restrict__ xq,
    float* __restrict__ rx, float* __restrict__ sxf) {
  const int row = blockIdx.x;
  const int tid = threadIdx.x;
  const float4* xr = (const float4*)(x + (long)row * K_DIM);
  float4 v[4];
  float mx = 0.f;
#pragma unroll
  for (int i = 0; i < 4; ++i) {
    v[i] = xr[i * 256 + tid];
    mx = fmaxf(mx, fmaxf(fmaxf(fabsf(v[i].x), fabsf(v[i].y)),
                         fmaxf(fabsf(v[i].z), fabsf(v[i].w))));
  }
#pragma unroll
  for (int off = 32; off > 0; off >>= 1) mx = fmaxf(mx, __shfl_down(mx, off, 64));
  __shared__ float redm[4];
  __shared__ int reds[4];
  const int lane = tid & 63, w = tid >> 6;
  if (lane == 0) redm[w] = mx;
  __syncthreads();
  const float maxv = fmaxf(fmaxf(redm[0], redm[1]), fmaxf(redm[2], redm[3]));
  const float inv = maxv > 0.f ? 127.f / maxv : 0.f;
  int* xo = (int*)(xq + (long)row * K_DIM);
  int ssum = 0;
#pragma unroll
  for (int i = 0; i < 4; ++i) {
    const int q0 = __float2int_rn(v[i].x * inv);
    const int q1 = __float2int_rn(v[i].y * inv);
    const int q2 = __float2int_rn(v[i].z * inv);
    const int q3 = __float2int_rn(v[i].w * inv);
    ssum += q0 + q1 + q2 + q3;
    xo[i * 256 + tid] =
        (q0 & 255) | ((q1 & 255) << 8) | ((q2 & 255) << 16) | ((q3 & 255) << 24);
  }
#pragma unroll
  for (int off = 32; off > 0; off >>= 1) ssum += __shfl_down(ssum, off, 64);
  if (lane == 0) reds[w] = ssum;
  __syncthreads();
  if (tid == 0) {
    rx[row] = maxv * (1.f / 127.f);
    sxf[row] = (float)(reds[0] + reds[1] + reds[2] + reds[3]);
  }
}

// ---------------- prep: qweight int32 [0,255] -> i8 (q-128), exact ----------------
__global__ __launch_bounds__(256) void prep_q_i8(
    const int* __restrict__ q, char* __restrict__ qb) {
  const long idx = (long)blockIdx.x * blockDim.x + threadIdx.x;  // one int4 -> one int
  const int4 v = ((const int4*)q)[idx];
  const int a = v.x - 128, b = v.y - 128, c = v.z - 128, d = v.w - 128;
  ((int*)qb)[idx] = (a & 255) | ((b & 255) << 8) | ((c & 255) << 16) | ((d & 255) << 24);
}

// ---------------- GEMM: 256x256, BK=128, i8 16x16x64 MFMA, 4 waves x (128x128) ----------------
// Serial-sum model (validated R6-R14: per-tile time = LDS-port + MFMA, never
// overlapped at HIP level): minimize the SUM. 4 waves of 128x128 wave-tile cut
// LDS read amplification from (128+64)x8 = 192 KB to (128+128)x4 = 128 KB per
// tile (A re-read x2 not x4), port time 2313 -> 1506 cyc. MFMA per SIMD is
// unchanged (1 wave x 128 MFMA = same total work). acc = 8x8 frags x4 = 256 AGPR,
// ~330 unified regs at __launch_bounds__(256,1) — under the 450 no-spill line.
// Geometry: conflict-free 128B rows (16x16 read pattern, R14-verified zero
// conflicts), XOR-(row&7) chunk swizzle both-sides, T1 XCD swizzle.
// Ledger: STAGE(t+1) = 16 loads (A 8, B 8). Steady in-flight at VMC = 32
// -> VMC(16) forces tile t's 16. Two barriers per tile.
__global__ __launch_bounds__(256, 1) void wq_gemm_i8(
    const char* __restrict__ A,             // xq [M][K] i8
    const char* __restrict__ B,             // qb [N][K] i8
    const float* __restrict__ rx,           // [M] row scale
    const float* __restrict__ sxf,          // [M] sum of xi (float, exact)
    const float* __restrict__ scales,       // [N]
    const float* __restrict__ zps,          // [N]
    const float* __restrict__ bias,         // [N]
    float* __restrict__ C) {                // [M][N]
  __shared__ __align__(16) char lds[2 * 65536];  // [buf][A:32KB | B:32KB]

  const int tid = threadIdx.x;
  const int lane = tid & 63;
  const int wv = tid >> 6;
  const int wr = wv >> 1, wc = wv & 1;  // 2x2 waves; wave tile 128x128

  // T1: XCD-aware chunked swizzle (nwg=512, 512%8==0).
  const int wg = blockIdx.x;
  const int lid = (wg & 7) * 64 + (wg >> 3);
  const int bx = lid & 15, by = lid >> 4;
  const int brow = by * BM;
  const int bcol = bx * BN;

  i32x4 acc[8][8] = {};  // 8 fm x 8 fn x 4 i32 = 256 AGPR

  // ---- staging: sweep = 256 thr x 16B = 4KB = 32 rows x 128B; 8 sweeps/matrix ----
  const int srow = tid >> 3;                           // 0..31 within sweep
  const int schunk = ((tid & 7) ^ (srow & 7)) * 16;    // pre-swizzled source chunk
  const int wub = (tid & ~63) * 16;                    // wave-uniform LDS base
  const char* gAs = A + (long)(brow + srow) * K_DIM + schunk;
  const char* gBs = B + (long)(bcol + srow) * K_DIM + schunk;

#define STAGE(T)                                                              \
  do {                                                                        \
    char* d = lds + ((T) & 1) * 65536;                                        \
    _Pragma("unroll") for (int j = 0; j < 8; ++j)                             \
      gload_lds16(gAs + (long)j * 131072 + (long)(T) * 128,                   \
                  d + j * 4096 + wub);                                        \
    _Pragma("unroll") for (int j = 0; j < 8; ++j)                             \
      gload_lds16(gBs + (long)j * 131072 + (long)(T) * 128,                   \
                  d + 32768 + j * 4096 + wub);                                \
  } while (0)

  // ---- fragment read offsets ----
  // 16x16x64 i8 operand: lane holds [row=lane&15][k = (lane>>4)*16 + 0..15].
  // chunk = ks*4+kq, XOR (row&7); fm/fn*16 rows and wr/wc*128 are ≡0 mod 8.
  const int row15 = lane & 15;
  const int kq = lane >> 4;  // 0..3
  int aoff[2], boff[2];
#pragma unroll
  for (int ks = 0; ks < 2; ++ks) {
    const int ch = ((ks * 4 + kq) ^ (row15 & 7)) * 16;
    aoff[ks] = (wr * 128 + row15) * 128 + ch;           // + fm*2048 (16 rows)
    boff[ks] = 32768 + (wc * 128 + row15) * 128 + ch;   // + fn*2048
  }

#define RD_A(BB, FM, KS) (*(const i32x4*)(lds + (BB) + aoff[KS] + (FM) * 2048))
#define RD_B(BB, FN, KS) (*(const i32x4*)(lds + (BB) + boff[KS] + (FN) * 2048))
#define MMA(FM, FN, AV, BV)                                                   \
  acc[FM][FN] = __builtin_amdgcn_mfma_i32_16x16x64_i8(AV, BV, acc[FM][FN], 0, 0, 0)

#define BAR() __builtin_amdgcn_s_barrier()
#define VMC(N)                                                                \
  do {                                                                        \
    asm volatile("s_waitcnt vmcnt(" #N ")");                                  \
    __builtin_amdgcn_sched_barrier(0);                                        \
  } while (0)

  // Compute one tile: read all B (16 b128), then per-fm: read 2 A + 16 MFMA.
#define COMPUTE(BB)                                                           \
  do {                                                                        \
    i32x4 bf[8][2];                                                           \
    _Pragma("unroll") for (int n = 0; n < 8; ++n)                             \
      _Pragma("unroll") for (int ks = 0; ks < 2; ++ks)                        \
        bf[n][ks] = RD_B(BB, n, ks);                                          \
    _Pragma("unroll") for (int f = 0; f < 8; ++f) {                           \
      i32x4 a0 = RD_A(BB, f, 0), a1 = RD_A(BB, f, 1);                         \
      _Pragma("unroll") for (int n = 0; n < 8; ++n) {                         \
        MMA(f, n, a0, bf[n][0]);                                              \
        MMA(f, n, a1, bf[n][1]);                                              \
      }                                                                       \
    }                                                                         \
  } while (0)

  // ---- prologue ----
  STAGE(0);
  VMC(0);
  BAR();

  // ---- main loop: tiles 0..NT2-2 ----
  for (int t = 0; t < NT2 - 1; ++t) {
    const int bb = (t & 1) * 65536;
    STAGE(t + 1);   // in-flight: t+1's 16 (t's already forced)
    VMC(16);        // steady state: forces tile t's 16; t+1's stay in flight
    BAR();
    COMPUTE(bb);
    BAR();          // all reads of buf done before next iter's STAGE overwrites
  }

  // ---- tail: tile NT2-1 ----
  {
    VMC(0);
    BAR();
    COMPUTE(((NT2 - 1) & 1) * 65536);
  }

  // ---- epilogue: 16x16 C/D layout col=lane&15, row=kq*4+j (m89-verified) ----
  // y = s * rx * (dot_i32 + (128 - zp) * sum_xi) + b
#pragma unroll
  for (int fm = 0; fm < 8; ++fm) {
    const int r0 = brow + wr * 128 + fm * 16 + kq * 4;
#pragma unroll
    for (int j = 0; j < 4; ++j) {
      const int grow = r0 + j;
      const float rxv = rx[grow];
      const float sxv = sxf[grow];
#pragma unroll
      for (int fn = 0; fn < 8; ++fn) {
        const int coln = bcol + wc * 128 + fn * 16 + row15;
        C[(long)grow * N_DIM + coln] =
            scales[coln] * rxv * ((float)acc[fm][fn][j] + (128.f - zps[coln]) * sxv) +
            bias[coln];
      }
    }
  }
}

// ---------------- launch ----------------
extern "C" void kernel_launch(void* const* d_in, const int* in_sizes, int n_in,
                              void* d_out, int out_size, void* d_ws, size_t ws_size,
                              hipStream_t stream) {
  const float* x = (const float*)d_in[0];
  const int* qw = (const int*)d_in[1];
  const float* scales = (const float*)d_in[2];
  const float* zps = (const float*)d_in[3];
  const float* bias = (const float*)d_in[4];
  float* out = (float*)d_out;

  char* ws = (char*)d_ws;
  char* xq = ws;                                             // 32 MB i8
  char* qb = ws + (size_t)32 * 1024 * 1024;                  // 16 MB i8
  float* rx = (float*)(ws + (size_t)48 * 1024 * 1024);       // 32 KB
  float* sxf = (float*)(ws + (size_t)48 * 1024 * 1024 + 65536);  // 32 KB

  hipLaunchKernelGGL(prep_x_i8, dim3(M_DIM), dim3(256), 0, stream, x, xq, rx, sxf);
  hipLaunchKernelGGL(prep_q_i8, dim3((N_DIM * K_DIM / 4) / 256), dim3(256), 0, stream,
                     qw, qb);
  hipLaunchKernelGGL(wq_gemm_i8, dim3((M_DIM / BM) * (N_DIM / BN)), dim3(256), 0,
                     stream, xq, qb, rx, sxf, scales, zps, bias, out);
}

// Round 16
// 179.783 us; speedup vs baseline: 1.4189x; 1.4189x over previous
//
#include <hip/hip_runtime.h>
#include <hip/hip_bf16.h>

// ---------------- common ----------------
typedef __attribute__((ext_vector_type(4))) int i32x4;

#define M_DIM 8192
#define N_DIM 4096
#define K_DIM 4096
#define BM 256
#define BN 256
#define BK 128
#define NT2 (K_DIM / BK)  // 32

static __device__ inline void gload_lds16(const void* g, void* l) {
  __builtin_amdgcn_global_load_lds(
      (const __attribute__((address_space(1))) unsigned int*)g,
      (__attribute__((address_space(3))) unsigned int*)l,
      16, 0, 0);
}

// ---------------- prep: x fp32 -> i8 (per-row symmetric), row scale + int row-sum ----------------
__global__ __launch_bounds__(256) void prep_x_i8(
    const float* __restrict__ x, char* __restrict__ xq,
    float* __restrict__ rx, float* __restrict__ sxf) {
  const int row = blockIdx.x;
  const int tid = threadIdx.x;
  const float4* xr = (const float4*)(x + (long)row * K_DIM);
  float4 v[4];
  float mx = 0.f;
#pragma unroll
  for (int i = 0; i < 4; ++i) {
    v[i] = xr[i * 256 + tid];
    mx = fmaxf(mx, fmaxf(fmaxf(fabsf(v[i].x), fabsf(v[i].y)),
                         fmaxf(fabsf(v[i].z), fabsf(v[i].w))));
  }
#pragma unroll
  for (int off = 32; off > 0; off >>= 1) mx = fmaxf(mx, __shfl_down(mx, off, 64));
  __shared__ float redm[4];
  __shared__ int reds[4];
  const int lane = tid & 63, w = tid >> 6;
  if (lane == 0) redm[w] = mx;
  __syncthreads();
  const float maxv = fmaxf(fmaxf(redm[0], redm[1]), fmaxf(redm[2], redm[3]));
  const float inv = maxv > 0.f ? 127.f / maxv : 0.f;
  int* xo = (int*)(xq + (long)row * K_DIM);
  int ssum = 0;
#pragma unroll
  for (int i = 0; i < 4; ++i) {
    const int q0 = __float2int_rn(v[i].x * inv);
    const int q1 = __float2int_rn(v[i].y * inv);
    const int q2 = __float2int_rn(v[i].z * inv);
    const int q3 = __float2int_rn(v[i].w * inv);
    ssum += q0 + q1 + q2 + q3;
    xo[i * 256 + tid] =
        (q0 & 255) | ((q1 & 255) << 8) | ((q2 & 255) << 16) | ((q3 & 255) << 24);
  }
#pragma unroll
  for (int off = 32; off > 0; off >>= 1) ssum += __shfl_down(ssum, off, 64);
  if (lane == 0) reds[w] = ssum;
  __syncthreads();
  if (tid == 0) {
    rx[row] = maxv * (1.f / 127.f);
    sxf[row] = (float)(reds[0] + reds[1] + reds[2] + reds[3]);
  }
}

// ---------------- prep: qweight int32 [0,255] -> i8 (q-128), exact ----------------
__global__ __launch_bounds__(256) void prep_q_i8(
    const int* __restrict__ q, char* __restrict__ qb) {
  const long idx = (long)blockIdx.x * blockDim.x + threadIdx.x;  // one int4 -> one int
  const int4 v = ((const int4*)q)[idx];
  const int a = v.x - 128, b = v.y - 128, c = v.z - 128, d = v.w - 128;
  ((int*)qb)[idx] = (a & 255) | ((b & 255) << 8) | ((c & 255) << 16) | ((d & 255) << 24);
}

// ---------------- GEMM: 256x256, BK=128, i8 16x16x64 MFMA (R14 best-known config) ----------------
// Local optimum verified across: schedule (4-phase/2-phase/reg-prefetch±setprio),
// MFMA shape (32x32x32 vs 16x16x64), occupancy (1 vs 2 blocks/CU), wave tile
// (128x64 vs 128x128), staging (LDS vs B-direct-to-reg). 16x16 read pattern is
// bank-conflict-FREE (R14: SQ_LDS_BANK_CONFLICT = 0; the 32x32 pattern's 4/read
// was structural). Serial-sum timing model: LDS-port + stage + MFMA ≈ 5160
// cyc/tile-slot, measured across 10 configs; DS∥MFMA overlap not achievable at
// plain-HIP level (m201 also fits serial-sum).
// Geometry: conflict-free 128B rows, XOR-(row&7) chunk swizzle both-sides
// (pre-swizzled global source, linear LDS dest per global_load_lds, same XOR on
// read — lane-constant, folds into base). 8 waves (2Mx4N), wave tile 128x64 =
// 8 fm x 4 fn; 64 MFMA + 24 ds_read_b128 per wave per tile.
// Ledger: per tile t: half1 stages G1(t+1) = {A0,A2,B0,B2,B1,B3} (6 loads),
// half2 stages G2(t+1) = {A1,A3} (2).
//   mid-tile:  in-flight = G2(t){2} + G1(t+1){6} -> VMC(6) forces G2(t)
//   boundary:  in-flight = G1(t+1){6} + G2(t+1){2} -> VMC(2) forces G1(t+1)
__global__ __launch_bounds__(512, 2) void wq_gemm_i8(
    const char* __restrict__ A,             // xq [M][K] i8
    const char* __restrict__ B,             // qb [N][K] i8
    const float* __restrict__ rx,           // [M] row scale
    const float* __restrict__ sxf,          // [M] sum of xi (float, exact)
    const float* __restrict__ scales,       // [N]
    const float* __restrict__ zps,          // [N]
    const float* __restrict__ bias,         // [N]
    float* __restrict__ C) {                // [M][N]
  __shared__ __align__(16) char lds[2 * 65536];  // [buf][A:32KB | B:32KB]

  const int tid = threadIdx.x;
  const int lane = tid & 63;
  const int wv = tid >> 6;
  const int wr = wv >> 2, wc = wv & 3;

  // T1: XCD-aware chunked swizzle (nwg=512, 512%8==0).
  const int wg = blockIdx.x;
  const int lid = (wg & 7) * 64 + (wg >> 3);
  const int bx = lid & 15, by = lid >> 4;
  const int brow = by * BM;
  const int bcol = bx * BN;

  i32x4 acc[8][4] = {};  // 8 fm x 4 fn x 4 i32 = 128 AGPR

  // ---- staging: sweep = 512 thr x 16B = 8KB = 64 rows x 128B; 4 sweeps per matrix ----
  const int srow = tid >> 3;                           // 0..63 within sweep
  const int schunk = ((tid & 7) ^ (srow & 7)) * 16;    // pre-swizzled source chunk
  const int wub = (tid & ~63) * 16;                    // wave-uniform LDS base
  const char* gAs = A + (long)(brow + srow) * K_DIM + schunk;
  const char* gBs = B + (long)(bcol + srow) * K_DIM + schunk;

#define STAGE_A2(T, J0, J1)                                                   \
  do {                                                                        \
    char* d = lds + ((T) & 1) * 65536;                                        \
    gload_lds16(gAs + (long)(J0) * 262144 + (long)(T) * 128,                  \
                d + (J0) * 8192 + wub);                                       \
    gload_lds16(gAs + (long)(J1) * 262144 + (long)(T) * 128,                  \
                d + (J1) * 8192 + wub);                                       \
  } while (0)
#define STAGE_B2(T, J0, J1)                                                   \
  do {                                                                        \
    char* d = lds + ((T) & 1) * 65536 + 32768;                                \
    gload_lds16(gBs + (long)(J0) * 262144 + (long)(T) * 128,                  \
                d + (J0) * 8192 + wub);                                       \
    gload_lds16(gBs + (long)(J1) * 262144 + (long)(T) * 128,                  \
                d + (J1) * 8192 + wub);                                       \
  } while (0)

  // ---- fragment read offsets ----
  // 16x16x64 i8 operand: lane holds [row=lane&15][k = (lane>>4)*16 + 0..15].
  // Byte offset within 128B row = ks*64 + kq*16 -> chunk = ks*4+kq, XOR (row&7)
  // (fm*16 and wr*128 are ≡0 mod 8, so the XOR term is lane-constant).
  const int row15 = lane & 15;
  const int kq = lane >> 4;  // 0..3
  int aoff[2], boff[2];
#pragma unroll
  for (int ks = 0; ks < 2; ++ks) {
    const int ch = ((ks * 4 + kq) ^ (row15 & 7)) * 16;
    aoff[ks] = (wr * 128 + row15) * 128 + ch;           // + fm*2048 (16 rows)
    boff[ks] = 32768 + (wc * 64 + row15) * 128 + ch;    // + fn*2048
  }

#define RD_A(BB, FM, KS) (*(const i32x4*)(lds + (BB) + aoff[KS] + (FM) * 2048))
#define RD_B(BB, FN, KS) (*(const i32x4*)(lds + (BB) + boff[KS] + (FN) * 2048))
#define MMA(FM, FN, AV, BV)                                                   \
  acc[FM][FN] = __builtin_amdgcn_mfma_i32_16x16x64_i8(AV, BV, acc[FM][FN], 0, 0, 0)

#define BAR() __builtin_amdgcn_s_barrier()
#define VMC(N)                                                                \
  do {                                                                        \
    asm volatile("s_waitcnt vmcnt(" #N ")");                                  \
    __builtin_amdgcn_sched_barrier(0);                                        \
  } while (0)

  // half: FM0 = base fm (0 or 4). Reads 8 A-frags + (half1 only) 8 B-frags; 32 MFMA.
#define HALF_MMA(BB, FM0, AF, BF)                                             \
  do {                                                                        \
    _Pragma("unroll") for (int f = 0; f < 4; ++f)                             \
      _Pragma("unroll") for (int ks = 0; ks < 2; ++ks)                        \
        AF[f][ks] = RD_A(BB, (FM0) + f, ks);                                  \
    _Pragma("unroll") for (int ks = 0; ks < 2; ++ks)                          \
      _Pragma("unroll") for (int f = 0; f < 4; ++f)                           \
        _Pragma("unroll") for (int n = 0; n < 4; ++n)                         \
          MMA((FM0) + f, n, AF[f][ks], BF[n][ks]);                            \
  } while (0)

  // ---- prologue: stage tile 0 into buf0 (G1 then G2 order) ----
  STAGE_A2(0, 0, 2);
  STAGE_B2(0, 0, 2);
  STAGE_B2(0, 1, 3);
  STAGE_A2(0, 1, 3);
  VMC(2);  // G1(0) landed; G2(0)={A1,A3} may fly until mid-tile VMC
  BAR();

  i32x4 af[4][2], bf[4][2];

  // ---- main loop: tiles 0..NT2-2, staging t+1 into other buf ----
  for (int t = 0; t < NT2 - 1; ++t) {
    const int bb = (t & 1) * 65536;
    const int t1 = t + 1;
    // ---- half1: fm 0..3 (A sweep 2wr in {0,2}) + all B ----
#pragma unroll
    for (int n = 0; n < 4; ++n)
#pragma unroll
      for (int ks = 0; ks < 2; ++ks) bf[n][ks] = RD_B(bb, n, ks);
    STAGE_A2(t1, 0, 2);      // G1(t+1): 6 loads
    STAGE_B2(t1, 0, 2);
    STAGE_B2(t1, 1, 3);
    HALF_MMA(bb, 0, af, bf);
    VMC(6);  // G2(t)={A1,A3} landed -> half2's A-sweep-{1,3} reads safe
    BAR();
    // ---- half2: fm 4..7 (A sweep 2wr+1 in {1,3}) ----
    STAGE_A2(t1, 1, 3);      // G2(t+1): 2 loads
    HALF_MMA(bb, 4, af, bf);
    VMC(2);  // G1(t+1) landed -> next half1 safe (G2(t+1) may fly)
    BAR();
  }

  // ---- tail: tile NT2-1 (odd -> buf1), no staging ----
  {
    const int bb = 65536;
#pragma unroll
    for (int n = 0; n < 4; ++n)
#pragma unroll
      for (int ks = 0; ks < 2; ++ks) bf[n][ks] = RD_B(bb, n, ks);
    HALF_MMA(bb, 0, af, bf);
    VMC(0);  // drain this tile's {A1,A3}
    BAR();
    HALF_MMA(bb, 4, af, bf);
  }

  // ---- epilogue: 16x16 C/D layout col=lane&15, row=kq*4+j (m89-verified) ----
  // y = s * rx * (dot_i32 + (128 - zp) * sum_xi) + b
  float sc[4], zp[4], bs[4];
  int coln[4];
#pragma unroll
  for (int fn = 0; fn < 4; ++fn) {
    coln[fn] = bcol + wc * 64 + fn * 16 + row15;
    sc[fn] = scales[coln[fn]];
    zp[fn] = 128.f - zps[coln[fn]];
    bs[fn] = bias[coln[fn]];
  }
#pragma unroll
  for (int fm = 0; fm < 8; ++fm) {
    const int r0 = brow + wr * 128 + fm * 16 + kq * 4;
#pragma unroll
    for (int j = 0; j < 4; ++j) {
      const int grow = r0 + j;
      const float rxv = rx[grow];
      const float sxv = sxf[grow];
#pragma unroll
      for (int fn = 0; fn < 4; ++fn) {
        C[(long)grow * N_DIM + coln[fn]] =
            sc[fn] * rxv * ((float)acc[fm][fn][j] + zp[fn] * sxv) + bs[fn];
      }
    }
  }
}

// ---------------- launch ----------------
extern "C" void kernel_launch(void* const* d_in, const int* in_sizes, int n_in,
                              void* d_out, int out_size, void* d_ws, size_t ws_size,
                              hipStream_t stream) {
  const float* x = (const float*)d_in[0];
  const int* qw = (const int*)d_in[1];
  const float* scales = (const float*)d_in[2];
  const float* zps = (const float*)d_in[3];
  const float* bias = (const float*)d_in[4];
  float* out = (float*)d_out;

  char* ws = (char*)d_ws;
  char* xq = ws;                                             // 32 MB i8
  char* qb = ws + (size_t)32 * 1024 * 1024;                  // 16 MB i8
  float* rx = (float*)(ws + (size_t)48 * 1024 * 1024);       // 32 KB
  float* sxf = (float*)(ws + (size_t)48 * 1024 * 1024 + 65536);  // 32 KB

  hipLaunchKernelGGL(prep_x_i8, dim3(M_DIM), dim3(256), 0, stream, x, xq, rx, sxf);
  hipLaunchKernelGGL(prep_q_i8, dim3((N_DIM * K_DIM / 4) / 256), dim3(256), 0, stream,
                     qw, qb);
  hipLaunchKernelGGL(wq_gemm_i8, dim3((M_DIM / BM) * (N_DIM / BN)), dim3(512), 0,
                     stream, xq, qb, rx, sxf, scales, zps, bias, out);
}